// Round 7
// baseline (896.288 us; speedup 1.0000x reference)
//
#include <hip/hip_runtime.h>
#include <hip/hip_bf16.h>

#define NB 8192
#define NE 100000

typedef __bf16 bf16x8 __attribute__((ext_vector_type(8)));
typedef float  f32x4  __attribute__((ext_vector_type(4)));

// ---- cross-lane helpers ---------------------------------------------------
template<int C>
__device__ __forceinline__ float dpp_mov(float v) {
  return __int_as_float(__builtin_amdgcn_update_dpp(
      0, __float_as_int(v), C, 0xF, 0xF, true));
}

// sum across each 16-lane group (DPP only, VALU pipe)
__device__ __forceinline__ float red16(float v) {
  v += dpp_mov<0xB1>(v);   // xor 1
  v += dpp_mov<0x4E>(v);   // xor 2
  v += dpp_mov<0x141>(v);  // row_half_mirror -> sum over 8
  v += dpp_mov<0x140>(v);  // row_mirror      -> sum over 16
  return v;
}

__device__ __forceinline__ float swz_xor16(float v) {
  return __int_as_float(__builtin_amdgcn_ds_swizzle(__float_as_int(v), 0x401F));
}

// overflow-free tanh: (1-e)/(1+e), e = exp(-2|x|) in (0,1]
__device__ __forceinline__ float fast_tanh(float x) {
  float e = __expf(-2.0f * fabsf(x));
  float t = (1.0f - e) * __builtin_amdgcn_rcpf(1.0f + e);
  return copysignf(t, x);
}

// ---- prep: pack W2 (= att_w rows 64..127) into MFMA B-fragment layout, and
// precompute qpart[rid][j] = sum_k qrel[rid][k] * att_w[k][j] for all 1000 rids.
__global__ void prep_kernel(const float* __restrict__ att_w,
                            const float* __restrict__ qrel,
                            __bf16* __restrict__ wsf,      // 8*2*64*8 bf16 = 16 KB
                            float*  __restrict__ qpart) {  // 1000*128 f32
  const int t = threadIdx.x;      // 128 threads
  const int bid = blockIdx.x;
  if (bid == 0) {
    for (int i = t; i < 8192; i += 128) {
      int e  = i & 7;
      int l  = (i >> 3) & 63;
      int ks = (i >> 9) & 1;
      int tc = i >> 10;
      int k = ks * 32 + ((l >> 4) << 3) + e;
      int j = tc * 16 + (l & 15);
      wsf[i] = (__bf16)att_w[(64 + k) * 128 + j];
    }
  } else {
    int rid = bid - 1;            // 0..999
    float acc = 0.f;
    for (int k = 0; k < 64; ++k)
      acc += qrel[rid * 64 + k] * att_w[k * 128 + t];
    qpart[rid * 128 + t] = acc;
  }
}

// ---- main: ONE WAVE = ONE batch row b. No __syncthreads anywhere. --------
__global__ __launch_bounds__(256, 4)
void attn_kernel(const float* __restrict__ inp,
                 const int*   __restrict__ nb,
                 const int*   __restrict__ qid_p,
                 const float* __restrict__ wgt,
                 const float* __restrict__ mlp,
                 const float* __restrict__ attv,
                 const __bf16* __restrict__ wsf,
                 const float* __restrict__ qpart_t,
                 float* __restrict__ out) {
  __shared__ float plogS[4][128];   // per-wave logits / out-staging
  __shared__ float awlS[4][128];    // per-wave attention weights

  const int t    = threadIdx.x;
  const int lane = t & 63;
  const int w    = t >> 6;
  const int r    = lane & 15;      // fragment row (lane&15)
  const int c    = lane >> 4;      // fragment k-chunk (lane>>4)
  const int b    = blockIdx.x * 4 + w;   // this wave's batch row

  float* plog = plogS[w];
  float* awl  = awlS[w];

  // ---- early independent loads (hide under phase A/B) ----
  const int qid = qid_p[b];
  float qpv[8], vv[8];
#pragma unroll
  for (int tc = 0; tc < 8; ++tc) {
    qpv[tc] = qpart_t[qid * 128 + tc * 16 + r];   // L2-hot 512 KB table
    vv[tc]  = attv[tc * 16 + r];
  }
  // softmax-phase data for rows (lane, lane+64)
  const int ent0 = nb[((size_t)b * 128 + lane) * 2 + 1];
  const int ent1 = nb[((size_t)b * 128 + lane + 64) * 2 + 1];
  float2 wA = reinterpret_cast<const float2*>(wgt)[(size_t)b * 128 + lane];
  float2 wB = reinterpret_cast<const float2*>(wgt)[(size_t)b * 128 + lane + 64];
  const float wr0 = wA.x / (wA.y + 1.0f);
  const float wr1 = wB.x / (wB.y + 1.0f);

  // ---- phase A: all 128 rows; T held in MFMA-A fragments ----
  // af[tr][ks] elem e  <->  T[tr*16 + r][ks*32 + c*8 + e]
  int2 re[8];
#pragma unroll
  for (int tr = 0; tr < 8; ++tr)
    re[tr] = *reinterpret_cast<const int2*>(&nb[((size_t)b * 128 + tr * 16 + r) * 2]);

  bf16x8 af[8][2];
#pragma unroll
  for (int tr = 0; tr < 8; ++tr) {
    const float* iptr = &inp[((size_t)b * 128 + tr * 16 + r) * 64 + c * 8];
    f32x4 iv0 = *reinterpret_cast<const f32x4*>(iptr);
    f32x4 iv1 = *reinterpret_cast<const f32x4*>(iptr + 4);
    f32x4 iv2 = *reinterpret_cast<const f32x4*>(iptr + 32);
    f32x4 iv3 = *reinterpret_cast<const f32x4*>(iptr + 36);
    const float* rptr = &mlp[(size_t)re[tr].x * 64 + c * 8];
    f32x4 rv0 = *reinterpret_cast<const f32x4*>(rptr);
    f32x4 rv1 = *reinterpret_cast<const f32x4*>(rptr + 4);
    f32x4 rv2 = *reinterpret_cast<const f32x4*>(rptr + 32);
    f32x4 rv3 = *reinterpret_cast<const f32x4*>(rptr + 36);
    float s1 = rv0[0]*rv0[0] + rv0[1]*rv0[1] + rv0[2]*rv0[2] + rv0[3]*rv0[3]
             + rv1[0]*rv1[0] + rv1[1]*rv1[1] + rv1[2]*rv1[2] + rv1[3]*rv1[3]
             + rv2[0]*rv2[0] + rv2[1]*rv2[1] + rv2[2]*rv2[2] + rv2[3]*rv2[3]
             + rv3[0]*rv3[0] + rv3[1]*rv3[1] + rv3[2]*rv3[2] + rv3[3]*rv3[3];
    float s2 = iv0[0]*rv0[0] + iv0[1]*rv0[1] + iv0[2]*rv0[2] + iv0[3]*rv0[3]
             + iv1[0]*rv1[0] + iv1[1]*rv1[1] + iv1[2]*rv1[2] + iv1[3]*rv1[3]
             + iv2[0]*rv2[0] + iv2[1]*rv2[1] + iv2[2]*rv2[2] + iv2[3]*rv2[3]
             + iv3[0]*rv3[0] + iv3[1]*rv3[1] + iv3[2]*rv3[2] + iv3[3]*rv3[3];
    // reduce across the 4 c-chunks (lanes r, r+16, r+32, r+48)
    s1 += swz_xor16(s1);  s2 += swz_xor16(s2);
    s1 += __shfl_xor(s1, 32, 64);
    s2 += __shfl_xor(s2, 32, 64);
    float f   = s2 / fmaxf(s1, 1e-24f);
    float msk = (re[tr].y >= NE) ? 0.0f : 1.0f;
    bf16x8 a0, a1;
#pragma unroll
    for (int j = 0; j < 4; ++j) {
      a0[j]     = (__bf16)((iv0[j] - f * rv0[j]) * msk);
      a0[j + 4] = (__bf16)((iv1[j] - f * rv1[j]) * msk);
      a1[j]     = (__bf16)((iv2[j] - f * rv2[j]) * msk);
      a1[j + 4] = (__bf16)((iv3[j] - f * rv3[j]) * msk);
    }
    af[tr][0] = a0;
    af[tr][1] = a1;
  }

  // ---- phase B: logits. per (tr,tc): acc = qpart; 2 MFMA; tanh-dot ----
  // LICM-opaque offset: stops the compiler hoisting all 16 W2-frags (64 VGPR)
  int wofs = 0;
  asm volatile("" : "+s"(wofs));
#pragma unroll
  for (int tr = 0; tr < 8; ++tr) {
    float p0 = 0.f, p1 = 0.f, p2 = 0.f, p3 = 0.f;
    const __bf16* wp = wsf + wofs + lane * 8;
#pragma unroll
    for (int tc = 0; tc < 8; ++tc) {
      bf16x8 b0 = *reinterpret_cast<const bf16x8*>(wp + (tc * 2 + 0) * 512);
      bf16x8 b1 = *reinterpret_cast<const bf16x8*>(wp + (tc * 2 + 1) * 512);
      float qv = qpv[tc];
      f32x4 acc = f32x4{qv, qv, qv, qv};
      acc = __builtin_amdgcn_mfma_f32_16x16x32_bf16(af[tr][0], b0, acc, 0, 0, 0);
      acc = __builtin_amdgcn_mfma_f32_16x16x32_bf16(af[tr][1], b1, acc, 0, 0, 0);
      float v = vv[tc];
      p0 += fast_tanh(acc[0]) * v;
      p1 += fast_tanh(acc[1]) * v;
      p2 += fast_tanh(acc[2]) * v;
      p3 += fast_tanh(acc[3]) * v;
    }
    p0 = red16(p0); p1 = red16(p1); p2 = red16(p2); p3 = red16(p3);
    if (r == 0) {
      int row = tr * 16 + c * 4;       // D layout: row = (lane>>4)*4 + reg
      plog[row + 0] = p0;
      plog[row + 1] = p1;
      plog[row + 2] = p2;
      plog[row + 3] = p3;
    }
  }
  asm volatile("s_waitcnt lgkmcnt(0)" ::: "memory");  // plog visible in-wave

  // ---- softmax over 128 rows (fully in-wave) ----
  {
    float l0 = plog[lane]      - ((ent0 == NE) ? 1e19f : 0.0f);
    float l1 = plog[lane + 64] - ((ent1 == NE) ? 1e19f : 0.0f);
    float m = fmaxf(l0, l1);
    m = fmaxf(m, __shfl_xor(m, 1, 64));
    m = fmaxf(m, __shfl_xor(m, 2, 64));
    m = fmaxf(m, __shfl_xor(m, 4, 64));
    m = fmaxf(m, __shfl_xor(m, 8, 64));
    m = fmaxf(m, __shfl_xor(m, 16, 64));
    m = fmaxf(m, __shfl_xor(m, 32, 64));
    float e0 = __expf(l0 - m), e1 = __expf(l1 - m);
    float s = e0 + e1;
    s += __shfl_xor(s, 1, 64);
    s += __shfl_xor(s, 2, 64);
    s += __shfl_xor(s, 4, 64);
    s += __shfl_xor(s, 8, 64);
    s += __shfl_xor(s, 16, 64);
    s += __shfl_xor(s, 32, 64);
    float rcp = __builtin_amdgcn_rcpf(s);
    float inv = rcp * (2.0f - s * rcp);            // NR-refined 1/s
    float a0 = e0 * inv + wr0;
    float a1 = e1 * inv + wr1;
    awl[lane]      = a0;
    awl[lane + 64] = a1;
    float* awout = out + (size_t)NB * 64;          // second output, flat-concat
    awout[(size_t)b * 128 + lane]      = a0;
    awout[(size_t)b * 128 + lane + 64] = a1;
  }
  asm volatile("s_waitcnt lgkmcnt(0)" ::: "memory");  // awl visible in-wave

  // ---- phase C: output[d] = sum_n T[n][d] * aw[n] (own wave only) ----
  {
    float po0[8] = {0,0,0,0,0,0,0,0};
    float po1[8] = {0,0,0,0,0,0,0,0};
#pragma unroll
    for (int tr = 0; tr < 8; ++tr) {
      float a = awl[tr * 16 + r];
      bf16x8 a0 = af[tr][0], a1 = af[tr][1];
#pragma unroll
      for (int e = 0; e < 8; ++e) {
        po0[e] += (float)a0[e] * a;
        po1[e] += (float)a1[e] * a;
      }
    }
#pragma unroll
    for (int e = 0; e < 8; ++e) {
      po0[e] = red16(po0[e]);        // reduce over the 16 r-lanes per c-group
      po1[e] = red16(po1[e]);
    }
    if (r == 0) {
#pragma unroll
      for (int e = 0; e < 8; ++e) {
        plog[c * 8 + e]      = po0[e];   // reuse plog region as out-staging
        plog[32 + c * 8 + e] = po1[e];
      }
    }
  }
  asm volatile("s_waitcnt lgkmcnt(0)" ::: "memory");
  out[(size_t)b * 64 + lane] = plog[lane];   // coalesced 256 B per wave
}

// ---- host ----------------------------------------------------------------
extern "C" void kernel_launch(void* const* d_in, const int* in_sizes, int n_in,
                              void* d_out, int out_size, void* d_ws, size_t ws_size,
                              hipStream_t stream) {
  const float* inp  = (const float*)d_in[0];
  const int*   nb   = (const int*)d_in[1];
  const int*   qid  = (const int*)d_in[2];
  const float* wgt  = (const float*)d_in[3];
  const float* mlp  = (const float*)d_in[4];
  const float* qrel = (const float*)d_in[5];
  const float* attw = (const float*)d_in[6];
  const float* attv = (const float*)d_in[7];
  float* out = (float*)d_out;

  // ws layout: [0,16384) bf16 B-fragments; [16384, 16384+512000) qpart f32
  __bf16* wsf   = (__bf16*)d_ws;
  float*  qpart = (float*)((char*)d_ws + 16384);

  prep_kernel<<<1001, 128, 0, stream>>>(attw, qrel, wsf, qpart);
  attn_kernel<<<NB / 4, 256, 0, stream>>>(inp, nb, qid, wgt, mlp, attv, wsf, qpart, out);
}

// Round 8
// 442.352 us; speedup vs baseline: 2.0262x; 2.0262x over previous
//
#include <hip/hip_runtime.h>
#include <hip/hip_bf16.h>

#define NB 8192
#define NE 100000

typedef __bf16 bf16x8 __attribute__((ext_vector_type(8)));
typedef float  f32x4  __attribute__((ext_vector_type(4)));

// ---- cross-lane helpers ---------------------------------------------------
template<int C>
__device__ __forceinline__ float dpp_mov(float v) {
  return __int_as_float(__builtin_amdgcn_update_dpp(
      0, __float_as_int(v), C, 0xF, 0xF, true));
}

// sum across each 16-lane group (DPP only, VALU pipe)
__device__ __forceinline__ float red16(float v) {
  v += dpp_mov<0xB1>(v);   // xor 1
  v += dpp_mov<0x4E>(v);   // xor 2
  v += dpp_mov<0x141>(v);  // row_half_mirror -> sum over 8
  v += dpp_mov<0x140>(v);  // row_mirror      -> sum over 16
  return v;
}

__device__ __forceinline__ float swz_xor16(float v) {
  return __int_as_float(__builtin_amdgcn_ds_swizzle(__float_as_int(v), 0x401F));
}

// overflow-free tanh: (1-e)/(1+e), e = exp(-2|x|) in (0,1]
__device__ __forceinline__ float fast_tanh(float x) {
  float e = __expf(-2.0f * fabsf(x));
  float t = (1.0f - e) * __builtin_amdgcn_rcpf(1.0f + e);
  return copysignf(t, x);
}

// ---- prep: pack W2 (= att_w rows 64..127) into MFMA B-fragment layout, and
// precompute qpart[rid][j] = sum_k qrel[rid][k] * att_w[k][j] for all 1000 rids.
__global__ void prep_kernel(const float* __restrict__ att_w,
                            const float* __restrict__ qrel,
                            __bf16* __restrict__ wsf,      // 8*2*64*8 bf16 = 16 KB
                            float*  __restrict__ qpart) {  // 1000*128 f32
  const int t = threadIdx.x;      // 128 threads
  const int bid = blockIdx.x;
  if (bid == 0) {
    for (int i = t; i < 8192; i += 128) {
      int e  = i & 7;
      int l  = (i >> 3) & 63;
      int ks = (i >> 9) & 1;
      int tc = i >> 10;
      int k = ks * 32 + ((l >> 4) << 3) + e;
      int j = tc * 16 + (l & 15);
      wsf[i] = (__bf16)att_w[(64 + k) * 128 + j];
    }
  } else {
    int rid = bid - 1;            // 0..999
    float acc = 0.f;
    for (int k = 0; k < 64; ++k)
      acc += qrel[rid * 64 + k] * att_w[k * 128 + t];
    qpart[rid * 128 + t] = acc;
  }
}

// ---- main: one block per batch row b; T in MFMA-fragment registers --------
__global__ __launch_bounds__(256, 4)
void attn_kernel(const float* __restrict__ inp,
                 const int*   __restrict__ nb,
                 const int*   __restrict__ qid_p,
                 const float* __restrict__ wgt,
                 const float* __restrict__ mlp,
                 const float* __restrict__ attv,
                 const __bf16* __restrict__ wsf,
                 const float* __restrict__ qpart_t,
                 float* __restrict__ out) {
  __shared__ __attribute__((aligned(16))) __bf16 wsL[8192];  // 16 KB W2 frags
  __shared__ float plog[128], awl[128];
  __shared__ float part[4][64];

  const int t    = threadIdx.x;
  const int lane = t & 63;
  const int w    = t >> 6;       // wave id 0..3
  const int r    = lane & 15;    // fragment row
  const int c    = lane >> 4;    // fragment k-chunk 0..3
  const int b    = blockIdx.x;

  // ---- stage W2 fragments into LDS (linear copy, 4 x 16B per thread) ----
#pragma unroll
  for (int i = 0; i < 4; ++i) {
    int idx = (i * 256 + t) * 8;
    *reinterpret_cast<bf16x8*>(&wsL[idx]) =
        *reinterpret_cast<const bf16x8*>(&wsf[idx]);
  }

  // this lane's softmax row + its weight-ratio (small, issued early)
  const int rown = w * 32 + (lane & 31);
  float2 w01 = reinterpret_cast<const float2*>(wgt)[(size_t)b * 128 + rown];
  const float wr = w01.x / (w01.y + 1.0f);

  // ---- phase A: projection in A-fragment layout (own 32 rows) ----
  // af[tr][ks] elem e  <->  T[w*32 + tr*16 + r][ks*32 + c*8 + e]
  bf16x8 af[2][2];
  int2 re[2];
#pragma unroll
  for (int tr = 0; tr < 2; ++tr)
    re[tr] = *reinterpret_cast<const int2*>(&nb[((size_t)b * 128 + w * 32 + tr * 16 + r) * 2]);
#pragma unroll
  for (int tr = 0; tr < 2; ++tr) {
    const float* iptr = &inp[((size_t)b * 128 + w * 32 + tr * 16 + r) * 64 + c * 8];
    f32x4 iv0 = *reinterpret_cast<const f32x4*>(iptr);
    f32x4 iv1 = *reinterpret_cast<const f32x4*>(iptr + 4);
    f32x4 iv2 = *reinterpret_cast<const f32x4*>(iptr + 32);
    f32x4 iv3 = *reinterpret_cast<const f32x4*>(iptr + 36);
    const float* rptr = &mlp[(size_t)re[tr].x * 64 + c * 8];
    f32x4 rv0 = *reinterpret_cast<const f32x4*>(rptr);
    f32x4 rv1 = *reinterpret_cast<const f32x4*>(rptr + 4);
    f32x4 rv2 = *reinterpret_cast<const f32x4*>(rptr + 32);
    f32x4 rv3 = *reinterpret_cast<const f32x4*>(rptr + 36);
    float s1 = rv0[0]*rv0[0] + rv0[1]*rv0[1] + rv0[2]*rv0[2] + rv0[3]*rv0[3]
             + rv1[0]*rv1[0] + rv1[1]*rv1[1] + rv1[2]*rv1[2] + rv1[3]*rv1[3]
             + rv2[0]*rv2[0] + rv2[1]*rv2[1] + rv2[2]*rv2[2] + rv2[3]*rv2[3]
             + rv3[0]*rv3[0] + rv3[1]*rv3[1] + rv3[2]*rv3[2] + rv3[3]*rv3[3];
    float s2 = iv0[0]*rv0[0] + iv0[1]*rv0[1] + iv0[2]*rv0[2] + iv0[3]*rv0[3]
             + iv1[0]*rv1[0] + iv1[1]*rv1[1] + iv1[2]*rv1[2] + iv1[3]*rv1[3]
             + iv2[0]*rv2[0] + iv2[1]*rv2[1] + iv2[2]*rv2[2] + iv2[3]*rv2[3]
             + iv3[0]*rv3[0] + iv3[1]*rv3[1] + iv3[2]*rv3[2] + iv3[3]*rv3[3];
    // reduce across the 4 c-chunks (lanes r, r+16, r+32, r+48)
    s1 += swz_xor16(s1);  s2 += swz_xor16(s2);
    s1 += __shfl_xor(s1, 32, 64);
    s2 += __shfl_xor(s2, 32, 64);
    float f   = s2 / fmaxf(s1, 1e-24f);
    float msk = (re[tr].y >= NE) ? 0.0f : 1.0f;
    bf16x8 a0, a1;
#pragma unroll
    for (int j = 0; j < 4; ++j) {
      a0[j]     = (__bf16)((iv0[j] - f * rv0[j]) * msk);
      a0[j + 4] = (__bf16)((iv1[j] - f * rv1[j]) * msk);
      a1[j]     = (__bf16)((iv2[j] - f * rv2[j]) * msk);
      a1[j + 4] = (__bf16)((iv3[j] - f * rv3[j]) * msk);
    }
    af[tr][0] = a0;
    af[tr][1] = a1;
  }
  __syncthreads();   // barrier 0 of 3: wsL staged (phase A already consumed its loads)

  // ---- phase B: logits for own 32 rows (W2 frags from LDS) ----
  const int qid = qid_p[b];
  float qpv[8], vv[8];
#pragma unroll
  for (int tc = 0; tc < 8; ++tc) {
    qpv[tc] = qpart_t[qid * 128 + tc * 16 + r];   // L2-hot 512 KB table
    vv[tc]  = attv[tc * 16 + r];
  }
  float p[2][4] = {{0,0,0,0},{0,0,0,0}};
#pragma unroll
  for (int tc = 0; tc < 8; ++tc) {
    bf16x8 b0 = *reinterpret_cast<const bf16x8*>(&wsL[(tc * 2 + 0) * 512 + lane * 8]);
    bf16x8 b1 = *reinterpret_cast<const bf16x8*>(&wsL[(tc * 2 + 1) * 512 + lane * 8]);
    float qv = qpv[tc];
    f32x4 acc0 = f32x4{qv, qv, qv, qv};    // D layout: col = lane&15 (all regs)
    f32x4 acc1 = f32x4{qv, qv, qv, qv};
    acc0 = __builtin_amdgcn_mfma_f32_16x16x32_bf16(af[0][0], b0, acc0, 0, 0, 0);
    acc1 = __builtin_amdgcn_mfma_f32_16x16x32_bf16(af[1][0], b0, acc1, 0, 0, 0);
    acc0 = __builtin_amdgcn_mfma_f32_16x16x32_bf16(af[0][1], b1, acc0, 0, 0, 0);
    acc1 = __builtin_amdgcn_mfma_f32_16x16x32_bf16(af[1][1], b1, acc1, 0, 0, 0);
    float v = vv[tc];
    p[0][0] += fast_tanh(acc0[0]) * v;
    p[0][1] += fast_tanh(acc0[1]) * v;
    p[0][2] += fast_tanh(acc0[2]) * v;
    p[0][3] += fast_tanh(acc0[3]) * v;
    p[1][0] += fast_tanh(acc1[0]) * v;
    p[1][1] += fast_tanh(acc1[1]) * v;
    p[1][2] += fast_tanh(acc1[2]) * v;
    p[1][3] += fast_tanh(acc1[3]) * v;
  }
#pragma unroll
  for (int tr = 0; tr < 2; ++tr) {
    float p0 = red16(p[tr][0]), p1 = red16(p[tr][1]);
    float p2 = red16(p[tr][2]), p3 = red16(p[tr][3]);
    if (r == 0) {
      int row = w * 32 + tr * 16 + c * 4;  // D layout: row = (lane>>4)*4 + reg
      plog[row + 0] = p0;
      plog[row + 1] = p1;
      plog[row + 2] = p2;
      plog[row + 3] = p3;
    }
  }
  __syncthreads();   // barrier 1 of 3: plog complete (softmax needs all rows)

  // ---- softmax: every wave computes m,s redundantly; aw for own rows ----
  {
    int e0i = nb[((size_t)b * 128 + lane) * 2 + 1];
    int e1i = nb[((size_t)b * 128 + lane + 64) * 2 + 1];
    float l0 = plog[lane]      - ((e0i == NE) ? 1e19f : 0.0f);
    float l1 = plog[lane + 64] - ((e1i == NE) ? 1e19f : 0.0f);
    float m = fmaxf(l0, l1);
    m = fmaxf(m, __shfl_xor(m, 1, 64));
    m = fmaxf(m, __shfl_xor(m, 2, 64));
    m = fmaxf(m, __shfl_xor(m, 4, 64));
    m = fmaxf(m, __shfl_xor(m, 8, 64));
    m = fmaxf(m, __shfl_xor(m, 16, 64));
    m = fmaxf(m, __shfl_xor(m, 32, 64));
    float e0 = __expf(l0 - m), e1 = __expf(l1 - m);
    float s = e0 + e1;
    s += __shfl_xor(s, 1, 64);
    s += __shfl_xor(s, 2, 64);
    s += __shfl_xor(s, 4, 64);
    s += __shfl_xor(s, 8, 64);
    s += __shfl_xor(s, 16, 64);
    s += __shfl_xor(s, 32, 64);
    float rcp = __builtin_amdgcn_rcpf(s);
    float inv = rcp * (2.0f - s * rcp);            // NR-refined 1/s
    if (lane < 32) {
      int eri = nb[((size_t)b * 128 + rown) * 2 + 1];
      float lg = plog[rown] - ((eri == NE) ? 1e19f : 0.0f);
      float aw = __expf(lg - m) * inv + wr;
      awl[rown] = aw;
      float* awout = out + (size_t)NB * 64;        // second output, flat-concat
      awout[(size_t)b * 128 + rown] = aw;          // coalesced per-wave slice
    }
  }
  // phase C reads awl only for THIS wave's rows -> in-wave fence suffices
  asm volatile("s_waitcnt lgkmcnt(0)" ::: "memory");

  // ---- phase C: own-rows partial of output[d] = sum_n T[n][d]*aw[n] ----
  {
    float po0[8] = {0,0,0,0,0,0,0,0};
    float po1[8] = {0,0,0,0,0,0,0,0};
#pragma unroll
    for (int tr = 0; tr < 2; ++tr) {
      float a = awl[w * 32 + tr * 16 + r];
      bf16x8 a0 = af[tr][0], a1 = af[tr][1];
#pragma unroll
      for (int e = 0; e < 8; ++e) {
        po0[e] += (float)a0[e] * a;
        po1[e] += (float)a1[e] * a;
      }
    }
#pragma unroll
    for (int e = 0; e < 8; ++e) {
      po0[e] = red16(po0[e]);        // reduce over the 16 r-lanes per c-group
      po1[e] = red16(po1[e]);
    }
    if (r == 0) {
#pragma unroll
      for (int e = 0; e < 8; ++e) {
        part[w][c * 8 + e]      = po0[e];
        part[w][32 + c * 8 + e] = po1[e];
      }
    }
  }
  __syncthreads();   // barrier 2 of 3: part complete
  if (t < 64)
    out[(size_t)b * 64 + t] = part[0][t] + part[1][t] + part[2][t] + part[3][t];
}

// ---- host ----------------------------------------------------------------
extern "C" void kernel_launch(void* const* d_in, const int* in_sizes, int n_in,
                              void* d_out, int out_size, void* d_ws, size_t ws_size,
                              hipStream_t stream) {
  const float* inp  = (const float*)d_in[0];
  const int*   nb   = (const int*)d_in[1];
  const int*   qid  = (const int*)d_in[2];
  const float* wgt  = (const float*)d_in[3];
  const float* mlp  = (const float*)d_in[4];
  const float* qrel = (const float*)d_in[5];
  const float* attw = (const float*)d_in[6];
  const float* attv = (const float*)d_in[7];
  float* out = (float*)d_out;

  // ws layout: [0,16384) bf16 B-fragments; [16384, 16384+512000) qpart f32
  __bf16* wsf   = (__bf16*)d_ws;
  float*  qpart = (float*)((char*)d_ws + 16384);

  prep_kernel<<<1001, 128, 0, stream>>>(attw, qrel, wsf, qpart);
  attn_kernel<<<NB, 256, 0, stream>>>(inp, nb, qid, wgt, mlp, attv, wsf, qpart, out);
}